// Round 5
// baseline (464.428 us; speedup 1.0000x reference)
//
#include <hip/hip_runtime.h>
#include <hip/hip_cooperative_groups.h>

namespace cg = cooperative_groups;

#define N_NODES 5000
#define N_EDGES 160000
#define HID 64
#define BATCH 512
#define NSLICE 128               // histogram/reorder slices
#define EPB (N_EDGES / NSLICE)   // 1250 edges per slice
#define STRIDE 256               // bucket stride (mean deg 32; overflow prob ~0)
#define MAXGRID 640

// ws layout (bytes):
//   0         blk_hist   128*5000 i32 (counts -> slice-exclusive offsets)
//   2560000   deg        5000 i32
//   2580000   sorted_src 5000*256 i32
//   7700000   h1         5000*64 f32
//   8980000   h_part     5000*64 f32
//   10260000  t_part     512*64 f32
//   10391072  Wl1T(256) Wr1T(256) Wl2T(4096) Wr2T(4096) Wc1hT(4096) f32

struct Params {
    const float *x; const int *ei; const float *task;
    const float *Wl1, *bl1, *Wr1, *Wl2, *bl2, *Wr2;
    const float *Wt1, *bt1, *Wt2, *bt2, *Wc1, *bc1, *Wc2, *bc2;
    float *out;
    int *blk_hist; int *deg; int *sorted_src;
    float *h1, *h_part, *t_part;
    float *Wl1T, *Wr1T, *Wl2T, *Wr2T, *Wc1hT;
};

__global__ __launch_bounds__(256, 2) void fused_kernel(Params p) {
    cg::grid_group grid = cg::this_grid();
    const int tid = threadIdx.x;
    const int nblk = gridDim.x;
    // 20 KB union: int histogram/cursor OR the 3 small float tiles (never both in one block)
    __shared__ union SM {
        int   ldsi[N_NODES];
        float s[3][4][64];
    } sm;

    // ---------------- Phase A: edge histograms + weight transposes + task MLP ----------
    for (int u = blockIdx.x; u < NSLICE + 4 + BATCH / 4; u += nblk) {
        if (u < NSLICE) {
            for (int i = tid; i < N_NODES; i += 256) sm.ldsi[i] = 0;
            __syncthreads();
            int base = u * EPB;
            for (int j = tid; j < EPB; j += 256)
                atomicAdd(&sm.ldsi[p.ei[N_EDGES + base + j]], 1);
            __syncthreads();
            for (int i = tid; i < N_NODES; i += 256)
                p.blk_hist[u * N_NODES + i] = sm.ldsi[i];
        } else if (u < NSLICE + 4) {
            int w = u - NSLICE;
            if (w == 0) {
                for (int idx = tid; idx < 4096; idx += 256) {
                    int k = idx >> 6, h = idx & 63;
                    p.Wl2T[idx] = p.Wl2[h * 64 + k];
                }
            } else if (w == 1) {
                for (int idx = tid; idx < 4096; idx += 256) {
                    int k = idx >> 6, h = idx & 63;
                    p.Wr2T[idx] = p.Wr2[h * 64 + k];
                }
            } else if (w == 2) {
                for (int idx = tid; idx < 4096; idx += 256) {
                    int k = idx >> 6, h = idx & 63;
                    p.Wc1hT[idx] = p.Wc1[h * 128 + k];
                }
            } else {
                int k = tid >> 6, h = tid & 63;
                p.Wl1T[tid] = p.Wl1[h * 4 + k];
                p.Wr1T[tid] = p.Wr1[h * 4 + k];
            }
        } else {
            // task MLP + t-half of classifier layer 1: 4 batch rows per unit
            int grp = tid >> 6, h = tid & 63;
            int b = (u - (NSLICE + 4)) * 4 + grp;
            float4 tf = ((const float4*)p.task)[b];
            float4 w1 = ((const float4*)p.Wt1)[h];
            float v = p.bt1[h] + tf.x * w1.x + tf.y * w1.y + tf.z * w1.z + tf.w * w1.w;
            sm.s[0][grp][h] = fmaxf(v, 0.f);
            __syncthreads();
            const float4* w2r = (const float4*)(p.Wt2 + h * 64);
            const float4* s1v = (const float4*)sm.s[0][grp];
            float v2 = p.bt2[h];
#pragma unroll
            for (int q = 0; q < 16; q++) {
                float4 w = w2r[q]; float4 s = s1v[q];
                v2 += s.x * w.x + s.y * w.y + s.z * w.z + s.w * w.w;
            }
            sm.s[1][grp][h] = v2;   // no relu on 2nd task layer
            __syncthreads();
            const float4* wc  = (const float4*)(p.Wc1 + h * 128 + 64);
            const float4* s2v = (const float4*)sm.s[1][grp];
            float pr = p.bc1[h];
#pragma unroll
            for (int q = 0; q < 16; q++) {
                float4 w = wc[q]; float4 s = s2v[q];
                pr += s.x * w.x + s.y * w.y + s.z * w.z + s.w * w.w;
            }
            p.t_part[b * 64 + h] = pr;
        }
        __syncthreads();   // smem reuse safety across units
    }
    grid.sync();

    // ---------------- Phase B: per-node exclusive prefix over slices + deg ----------
    for (int n = blockIdx.x * 256 + tid; n < N_NODES; n += nblk * 256) {
        int run = 0;
#pragma unroll 8
        for (int b = 0; b < NSLICE; b++) {
            int v = p.blk_hist[b * N_NODES + n];   // coalesced
            p.blk_hist[b * N_NODES + n] = run;
            run += v;
        }
        p.deg[n] = run;
    }
    grid.sync();

    // ---------------- Phase C: counting-sort into fixed-stride buckets ----------
    for (int u = blockIdx.x; u < NSLICE; u += nblk) {
        for (int i = tid; i < N_NODES; i += 256) sm.ldsi[i] = 0;
        __syncthreads();
        int base = u * EPB;
        const int* excl = p.blk_hist + u * N_NODES;
        for (int j = tid; j < EPB; j += 256) {
            int src = p.ei[base + j];
            int dst = p.ei[N_EDGES + base + j];
            int local = atomicAdd(&sm.ldsi[dst], 1);   // LDS atomic
            p.sorted_src[dst * STRIDE + excl[dst] + local] = src;
        }
        __syncthreads();
    }
    grid.sync();

    // ---------------- Phase D: SAGE layer 1 (4 -> 64), 4 nodes per unit ----------
    {
        int lane = tid & 63, grp = tid >> 6;
        int f = lane & 3, g = lane >> 2;
        for (int q = blockIdx.x; q < N_NODES / 4; q += nblk) {
            int n = q * 4 + grp;
            int d = p.deg[n];
            const int* bucket = p.sorted_src + n * STRIDE;
            float acc = 0.f;
            for (int j = g; j < d; j += 16) acc += p.x[bucket[j] * 4 + f];
            acc += __shfl_down(acc, 32);
            acc += __shfl_down(acc, 16);
            acc += __shfl_down(acc, 8);
            acc += __shfl_down(acc, 4);
            if (lane < 4) {
                sm.s[0][grp][lane] = acc / fmaxf((float)d, 1.f);
                sm.s[1][grp][lane] = p.x[n * 4 + lane];
            }
            __syncthreads();
            float v = p.bl1[lane];
#pragma unroll
            for (int ff = 0; ff < 4; ff++)
                v += sm.s[0][grp][ff] * p.Wl1T[ff * 64 + lane]
                   + sm.s[1][grp][ff] * p.Wr1T[ff * 64 + lane];
            p.h1[n * 64 + lane] = fmaxf(v, 0.f);
            __syncthreads();   // protect smem before next iteration
        }
    }
    grid.sync();

    // ---------------- Phase E: layer 2 (64 -> 64) fused with h_part = h2 @ Wc1[:,:64].T
    {
        int h = tid & 63, grp = tid >> 6;
        for (int q = blockIdx.x; q < N_NODES / 4; q += nblk) {
            int n = q * 4 + grp;
            int d = p.deg[n];
            const int* bucket = p.sorted_src + n * STRIDE;
            float a0 = 0.f, a1 = 0.f, a2 = 0.f, a3 = 0.f;
            int j = 0;
            for (; j + 4 <= d; j += 4) {
                int e0 = bucket[j], e1 = bucket[j + 1], e2 = bucket[j + 2], e3 = bucket[j + 3];
                a0 += p.h1[e0 * 64 + h];
                a1 += p.h1[e1 * 64 + h];
                a2 += p.h1[e2 * 64 + h];
                a3 += p.h1[e3 * 64 + h];
            }
            for (; j < d; j++) a0 += p.h1[bucket[j] * 64 + h];
            float m = (a0 + a1 + a2 + a3) / fmaxf((float)d, 1.f);

            sm.s[0][grp][h] = m;
            sm.s[1][grp][h] = p.h1[n * 64 + h];
            __syncthreads();
            float v = p.bl2[h];
#pragma unroll
            for (int k = 0; k < 64; k++)
                v += sm.s[0][grp][k] * p.Wl2T[k * 64 + h]
                   + sm.s[1][grp][k] * p.Wr2T[k * 64 + h];
            __syncthreads();                 // all reads of s[0]/s[1] done
            sm.s[2][grp][h] = fmaxf(v, 0.f);
            __syncthreads();
            float pr = 0.f;
#pragma unroll
            for (int k = 0; k < 64; k++) pr += sm.s[2][grp][k] * p.Wc1hT[k * 64 + h];
            p.h_part[n * 64 + h] = pr;
            __syncthreads();                 // protect s[2] before next iteration
        }
    }
    grid.sync();

    // ---------------- Phase F: scores[b,n] = sum_h relu(hp+tp)*Wc2[h] + bc2 ----------
    for (int u = blockIdx.x; u < 640; u += nblk) {
        int nt = u % 20, bt = u / 20;        // 20 n-tiles x 32 b-tiles
        int n = nt * 256 + tid;
        bool valid = n < N_NODES;
        int nn = valid ? n : (N_NODES - 1);
        float hr[64];
        const float4* hp = (const float4*)(p.h_part + nn * 64);
#pragma unroll
        for (int i = 0; i < 16; i++) {
            float4 v = hp[i];
            hr[4 * i + 0] = v.x; hr[4 * i + 1] = v.y;
            hr[4 * i + 2] = v.z; hr[4 * i + 3] = v.w;
        }
        float b2 = p.bc2[0];
        int b0 = bt * 16;
        for (int bb = 0; bb < 16; bb++) {
            const float* tp = p.t_part + (b0 + bb) * 64;   // block-uniform address
            float acc = 0.f;
#pragma unroll
            for (int h = 0; h < 64; h++)
                acc = fmaf(fmaxf(hr[h] + tp[h], 0.f), p.Wc2[h], acc);
            if (valid) p.out[(b0 + bb) * N_NODES + n] = acc + b2;
        }
    }
}

// ---------- launch ----------
extern "C" void kernel_launch(void* const* d_in, const int* in_sizes, int n_in,
                              void* d_out, int out_size, void* d_ws, size_t ws_size,
                              hipStream_t stream) {
    char* ws = (char*)d_ws;
    Params p;
    p.x    = (const float*)d_in[0];
    p.ei   = (const int*)d_in[1];
    p.task = (const float*)d_in[2];
    p.Wl1  = (const float*)d_in[3];
    p.bl1  = (const float*)d_in[4];
    p.Wr1  = (const float*)d_in[5];
    p.Wl2  = (const float*)d_in[6];
    p.bl2  = (const float*)d_in[7];
    p.Wr2  = (const float*)d_in[8];
    p.Wt1  = (const float*)d_in[9];
    p.bt1  = (const float*)d_in[10];
    p.Wt2  = (const float*)d_in[11];
    p.bt2  = (const float*)d_in[12];
    p.Wc1  = (const float*)d_in[13];
    p.bc1  = (const float*)d_in[14];
    p.Wc2  = (const float*)d_in[15];
    p.bc2  = (const float*)d_in[16];
    p.out  = (float*)d_out;
    p.blk_hist   = (int*)(ws + 0);
    p.deg        = (int*)(ws + 2560000);
    p.sorted_src = (int*)(ws + 2580000);
    p.h1         = (float*)(ws + 7700000);
    p.h_part     = (float*)(ws + 8980000);
    p.t_part     = (float*)(ws + 10260000);
    p.Wl1T  = (float*)(ws + 10391072);
    p.Wr1T  = (float*)(ws + 10392096);
    p.Wl2T  = (float*)(ws + 10393120);
    p.Wr2T  = (float*)(ws + 10409504);
    p.Wc1hT = (float*)(ws + 10425888);

    // Ask the runtime how many blocks are actually co-residable; never exceed it.
    int maxb = 0;
    hipOccupancyMaxActiveBlocksPerMultiprocessor(&maxb, (const void*)fused_kernel, 256, 0);
    if (maxb < 1) maxb = 1;
    long long grid = (long long)maxb * 256;   // 256 CUs on MI355X
    if (grid > MAXGRID) grid = MAXGRID;

    void* args[] = { (void*)&p };
    hipLaunchCooperativeKernel((const void*)fused_kernel, dim3((unsigned)grid), dim3(256),
                               args, 0, stream);
}

// Round 6
// 152.919 us; speedup vs baseline: 3.0371x; 3.0371x over previous
//
#include <hip/hip_runtime.h>

#define N_NODES 5000
#define N_EDGES 160000
#define HID 64
#define BATCH 512
#define NSLICE 128               // histogram/reorder slices (128 CUs busy)
#define EPB (N_EDGES / NSLICE)   // 1250 edges per slice
#define STRIDE 128               // bucket stride (mean deg 32, sigma 5.7 -> 17 sigma margin)

// ws layout (bytes):
//   0        blk_hist   128*5000 i32 (counts -> slice-exclusive offsets)
//   2560000  deg        5000 i32
//   2580000  sorted_src 5000*128 i32
//   5140000  h1         5000*64 f32
//   6420000  h_part     5000*64 f32
//   7700000  t_part     512*64 f32
//   7831072  Wl1T(256) Wr1T(256) Wl2T(4096) Wr2T(4096) Wc1hT(4096) f32

// ---------- dispatch 1: per-slice edge histograms + weight transposes + task MLP ----------
__global__ __launch_bounds__(256) void prep_kernel(
        const int* __restrict__ ei,
        const float* __restrict__ Wl1, const float* __restrict__ Wr1,
        const float* __restrict__ Wl2, const float* __restrict__ Wr2,
        const float* __restrict__ Wc1,
        const float* __restrict__ task_feat,
        const float* __restrict__ Wt1, const float* __restrict__ bt1,
        const float* __restrict__ Wt2, const float* __restrict__ bt2,
        const float* __restrict__ bc1,
        int* __restrict__ blk_hist,
        float* __restrict__ Wl1T, float* __restrict__ Wr1T,
        float* __restrict__ Wl2T, float* __restrict__ Wr2T,
        float* __restrict__ Wc1hT, float* __restrict__ t_part) {
    int tid = threadIdx.x;
    int blk = blockIdx.x;
    __shared__ int hist[N_NODES];          // 20 KB, used only by blocks 0..127
    __shared__ float s1[4][64], s2[4][64]; // used only by task blocks

    if (blk < NSLICE) {
        for (int i = tid; i < N_NODES; i += 256) hist[i] = 0;
        __syncthreads();
        int base = blk * EPB;
        for (int j = tid; j < EPB; j += 256)
            atomicAdd(&hist[ei[N_EDGES + base + j]], 1);
        __syncthreads();
        for (int i = tid; i < N_NODES; i += 256)
            blk_hist[blk * N_NODES + i] = hist[i];
    } else if (blk == NSLICE) {
        for (int idx = tid; idx < 4096; idx += 256) {
            int k = idx >> 6, h = idx & 63;
            Wl2T[idx] = Wl2[h * 64 + k];
        }
    } else if (blk == NSLICE + 1) {
        for (int idx = tid; idx < 4096; idx += 256) {
            int k = idx >> 6, h = idx & 63;
            Wr2T[idx] = Wr2[h * 64 + k];
        }
    } else if (blk == NSLICE + 2) {
        for (int idx = tid; idx < 4096; idx += 256) {
            int k = idx >> 6, h = idx & 63;
            Wc1hT[idx] = Wc1[h * 128 + k];
        }
    } else if (blk == NSLICE + 3) {
        int k = tid >> 6, h = tid & 63;
        Wl1T[tid] = Wl1[h * 4 + k];
        Wr1T[tid] = Wr1[h * 4 + k];
    } else {
        // task MLP + t-half of classifier layer 1: 4 batch rows per block
        int grp = tid >> 6, h = tid & 63;
        int b = (blk - (NSLICE + 4)) * 4 + grp;
        float4 tf = ((const float4*)task_feat)[b];
        float4 w1 = ((const float4*)Wt1)[h];
        float v = bt1[h] + tf.x * w1.x + tf.y * w1.y + tf.z * w1.z + tf.w * w1.w;
        s1[grp][h] = fmaxf(v, 0.f);
        __syncthreads();
        const float4* w2r = (const float4*)(Wt2 + h * 64);
        const float4* s1v = (const float4*)s1[grp];
        float v2 = bt2[h];
#pragma unroll
        for (int q = 0; q < 16; q++) {
            float4 w = w2r[q]; float4 s = s1v[q];
            v2 += s.x * w.x + s.y * w.y + s.z * w.z + s.w * w.w;
        }
        s2[grp][h] = v2;   // no relu on 2nd task layer
        __syncthreads();
        const float4* wc  = (const float4*)(Wc1 + h * 128 + 64);
        const float4* s2v = (const float4*)s2[grp];
        float p = bc1[h];
#pragma unroll
        for (int q = 0; q < 16; q++) {
            float4 w = wc[q]; float4 s = s2v[q];
            p += s.x * w.x + s.y * w.y + s.z * w.z + s.w * w.w;
        }
        t_part[b * 64 + h] = p;
    }
}

// ---------- dispatch 2: per-node exclusive prefix over slices + deg ----------
__global__ __launch_bounds__(256) void offsets_kernel(int* __restrict__ blk_hist,
                                                      int* __restrict__ deg) {
    int n = blockIdx.x * 256 + threadIdx.x;
    if (n >= N_NODES) return;
    int run = 0;
#pragma unroll 8
    for (int b = 0; b < NSLICE; b++) {
        int v = blk_hist[b * N_NODES + n];   // coalesced across lanes
        blk_hist[b * N_NODES + n] = run;
        run += v;
    }
    deg[n] = run;
}

// ---------- dispatch 3: counting-sort edges into fixed-stride buckets ----------
__global__ __launch_bounds__(256) void reorder_kernel(
        const int* __restrict__ ei, const int* __restrict__ blk_hist,
        int* __restrict__ sorted_src) {
    __shared__ int cur[N_NODES];
    int tid = threadIdx.x;
    int blk = blockIdx.x;
    for (int i = tid; i < N_NODES; i += 256) cur[i] = 0;
    __syncthreads();
    int base = blk * EPB;
    const int* my_excl = blk_hist + blk * N_NODES;
    for (int j = tid; j < EPB; j += 256) {
        int src = ei[base + j];
        int dst = ei[N_EDGES + base + j];
        int local = atomicAdd(&cur[dst], 1);       // LDS atomic — fast
        sorted_src[dst * STRIDE + my_excl[dst] + local] = src;
    }
}

// ---------- dispatch 4: SAGE layer 1 (4 -> 64), bucket gather, 4 nodes/block ----------
__global__ __launch_bounds__(256) void layer1_kernel(
        const float* __restrict__ x, const int* __restrict__ deg,
        const int* __restrict__ sorted_src,
        const float* __restrict__ Wl1T, const float* __restrict__ bl1,
        const float* __restrict__ Wr1T, float* __restrict__ h1) {
    int lane = threadIdx.x & 63, grp = threadIdx.x >> 6;
    int n = blockIdx.x * 4 + grp;
    int d = deg[n];
    int f = lane & 3, g = lane >> 2;               // 16 neighbor slots x 4 features
    const int* bucket = sorted_src + n * STRIDE;
    float acc = 0.f;
    for (int j = g; j < d; j += 16) acc += x[bucket[j] * 4 + f];
    acc += __shfl_down(acc, 32);
    acc += __shfl_down(acc, 16);
    acc += __shfl_down(acc, 8);
    acc += __shfl_down(acc, 4);
    __shared__ float mean[4][4], xn[4][4];
    if (lane < 4) {
        mean[grp][lane] = acc / fmaxf((float)d, 1.f);  // lane == f here
        xn[grp][lane] = x[n * 4 + lane];
    }
    __syncthreads();
    float v = bl1[lane];
#pragma unroll
    for (int ff = 0; ff < 4; ff++)
        v += mean[grp][ff] * Wl1T[ff * 64 + lane] + xn[grp][ff] * Wr1T[ff * 64 + lane];
    h1[n * 64 + lane] = fmaxf(v, 0.f);
}

// ---------- dispatch 5: SAGE layer 2 (64 -> 64) fused with h_part = h2 @ Wc1[:,:64].T ----
__global__ __launch_bounds__(256) void layer2_kernel(
        const float* __restrict__ h1, const int* __restrict__ deg,
        const int* __restrict__ sorted_src,
        const float* __restrict__ Wl2T, const float* __restrict__ bl2,
        const float* __restrict__ Wr2T, const float* __restrict__ Wc1hT,
        float* __restrict__ h_part) {
    int h = threadIdx.x & 63, grp = threadIdx.x >> 6;
    int n = blockIdx.x * 4 + grp;
    int d = deg[n];
    const int* bucket = sorted_src + n * STRIDE;
    float a0 = 0.f, a1 = 0.f, a2 = 0.f, a3 = 0.f;
    int j = 0;
    for (; j + 4 <= d; j += 4) {
        int e0 = bucket[j], e1 = bucket[j + 1], e2 = bucket[j + 2], e3 = bucket[j + 3];
        a0 += h1[e0 * 64 + h];
        a1 += h1[e1 * 64 + h];
        a2 += h1[e2 * 64 + h];
        a3 += h1[e3 * 64 + h];
    }
    for (; j < d; j++) a0 += h1[bucket[j] * 64 + h];
    float m = (a0 + a1 + a2 + a3) / fmaxf((float)d, 1.f);

    __shared__ float shm[4][64], shh[4][64], shh2[4][64];
    shm[grp][h] = m;
    shh[grp][h] = h1[n * 64 + h];
    __syncthreads();
    float v = bl2[h];
#pragma unroll
    for (int k = 0; k < 64; k++)
        v += shm[grp][k] * Wl2T[k * 64 + h] + shh[grp][k] * Wr2T[k * 64 + h];
    shh2[grp][h] = fmaxf(v, 0.f);
    __syncthreads();
    float p = 0.f;
#pragma unroll
    for (int k = 0; k < 64; k++) p += shh2[grp][k] * Wc1hT[k * 64 + h];
    h_part[n * 64 + h] = p;
}

// ---------- dispatch 6: scores[b,n] = sum_h relu(hp[n,h]+tp[b,h])*Wc2[h] + bc2 ----------
__global__ __launch_bounds__(256) void scores_kernel(
        const float* __restrict__ h_part, const float* __restrict__ t_part,
        const float* __restrict__ Wc2, const float* __restrict__ bc2,
        float* __restrict__ out) {
    int tid = threadIdx.x;
    int n = blockIdx.x * 256 + tid;
    bool valid = n < N_NODES;
    int nn = valid ? n : (N_NODES - 1);
    float hr[64];
    const float4* hp = (const float4*)(h_part + nn * 64);
#pragma unroll
    for (int i = 0; i < 16; i++) {
        float4 v = hp[i];
        hr[4 * i + 0] = v.x; hr[4 * i + 1] = v.y;
        hr[4 * i + 2] = v.z; hr[4 * i + 3] = v.w;
    }
    float b2 = bc2[0];
    int b0 = blockIdx.y * 8;                       // 64 b-tiles of 8
    for (int bb = 0; bb < 8; bb++) {
        const float* tp = t_part + (b0 + bb) * 64; // block-uniform address -> s_loads
        float acc = 0.f;
#pragma unroll
        for (int h = 0; h < 64; h++)
            acc = fmaf(fmaxf(hr[h] + tp[h], 0.f), Wc2[h], acc);
        if (valid) out[(b0 + bb) * N_NODES + n] = acc + b2;
    }
}

// ---------- launch ----------
extern "C" void kernel_launch(void* const* d_in, const int* in_sizes, int n_in,
                              void* d_out, int out_size, void* d_ws, size_t ws_size,
                              hipStream_t stream) {
    const float* x    = (const float*)d_in[0];
    const int*   ei   = (const int*)d_in[1];
    const float* task = (const float*)d_in[2];
    const float* Wl1  = (const float*)d_in[3];
    const float* bl1  = (const float*)d_in[4];
    const float* Wr1  = (const float*)d_in[5];
    const float* Wl2  = (const float*)d_in[6];
    const float* bl2  = (const float*)d_in[7];
    const float* Wr2  = (const float*)d_in[8];
    const float* Wt1  = (const float*)d_in[9];
    const float* bt1  = (const float*)d_in[10];
    const float* Wt2  = (const float*)d_in[11];
    const float* bt2  = (const float*)d_in[12];
    const float* Wc1  = (const float*)d_in[13];
    const float* bc1  = (const float*)d_in[14];
    const float* Wc2  = (const float*)d_in[15];
    const float* bc2  = (const float*)d_in[16];
    float* out = (float*)d_out;

    char* ws = (char*)d_ws;
    int*   blk_hist   = (int*)(ws + 0);
    int*   deg        = (int*)(ws + 2560000);
    int*   sorted_src = (int*)(ws + 2580000);
    float* h1         = (float*)(ws + 5140000);
    float* h_part     = (float*)(ws + 6420000);
    float* t_part     = (float*)(ws + 7700000);
    float* Wl1T  = (float*)(ws + 7831072);
    float* Wr1T  = (float*)(ws + 7832096);
    float* Wl2T  = (float*)(ws + 7833120);
    float* Wr2T  = (float*)(ws + 7849504);
    float* Wc1hT = (float*)(ws + 7865888);

    prep_kernel<<<NSLICE + 4 + BATCH / 4, 256, 0, stream>>>(
        ei, Wl1, Wr1, Wl2, Wr2, Wc1, task, Wt1, bt1, Wt2, bt2, bc1,
        blk_hist, Wl1T, Wr1T, Wl2T, Wr2T, Wc1hT, t_part);
    offsets_kernel<<<(N_NODES + 255) / 256, 256, 0, stream>>>(blk_hist, deg);
    reorder_kernel<<<NSLICE, 256, 0, stream>>>(ei, blk_hist, sorted_src);
    layer1_kernel<<<N_NODES / 4, 256, 0, stream>>>(x, deg, sorted_src, Wl1T, bl1, Wr1T, h1);
    layer2_kernel<<<N_NODES / 4, 256, 0, stream>>>(h1, deg, sorted_src, Wl2T, bl2, Wr2T,
                                                   Wc1hT, h_part);
    scores_kernel<<<dim3(20, 64), 256, 0, stream>>>(h_part, t_part, Wc2, bc2, out);
}